// Round 1
// baseline (6681.108 us; speedup 1.0000x reference)
//
#include <hip/hip_runtime.h>
#include <math.h>

#define N_HID   1024
#define NBATCH  128
#define TSTEPS  500
#define DT      0.05f
#define THETA   0.1f

// tiling
#define COLS_PER_WG   32
#define BATCH_PER_WG  8
#define NCOL_TILES    (N_HID / COLS_PER_WG)     // 32
#define NBATCH_TILES  (NBATCH / BATCH_PER_WG)   // 16
#define NWG           (NCOL_TILES * NBATCH_TILES) // 512
#define KSPLIT        8
#define KSEG          (N_HID / KSPLIT)          // 128

// One timestep: C = hyIn @ W  (+ input + bias, tanh), then oscillator update,
// spike, LI filter, integer spike-count accumulation.
__global__ __launch_bounds__(256, 2) void step_kernel(
    const float* __restrict__ x,
    const float* __restrict__ W,      // h2h, (1024, 1024) row-major
    const float* __restrict__ x2h,    // (1, 1024)
    const float* __restrict__ bias,
    const float* __restrict__ gam,
    const float* __restrict__ eps,
    const float* __restrict__ hyIn,
    float* __restrict__ hyOut,
    float* __restrict__ hz,
    float* __restrict__ u,
    unsigned int* __restrict__ tot,
    int t, float alpha, float oma)
{
    __shared__ float4 sh_hy4[BATCH_PER_WG * (N_HID / 4)]; // 32 KB
    __shared__ float  sh_part[KSPLIT * BATCH_PER_WG * COLS_PER_WG]; // 8 KB
    __shared__ unsigned int sh_cnt;

    const int tid = threadIdx.x;
    if (tid == 0) sh_cnt = 0u;

    // XCD-aware swizzle: XCD (wg%8) gets 4 consecutive col-tiles -> a
    // contiguous 128-column slice of W stays hot in that XCD's L2.
    const int wg  = blockIdx.x;
    const int xcd = wg & 7;
    const int idx = wg >> 3;           // 0..63
    const int ct  = xcd * 4 + (idx & 3);   // 0..31 col tile
    const int bt  = idx >> 2;              // 0..15 batch tile
    const int cbase = ct * COLS_PER_WG;
    const int bbase = bt * BATCH_PER_WG;

    // stage hy tile (8 x 1024 f32 = 32 KB), contiguous + coalesced
    {
        const float4* hy4 = (const float4*)(hyIn + (size_t)bbase * N_HID);
        #pragma unroll
        for (int i = 0; i < (BATCH_PER_WG * (N_HID / 4)) / 256; ++i)
            sh_hy4[i * 256 + tid] = hy4[i * 256 + tid];
    }
    __syncthreads();

    const int j   = tid & 31;          // column lane within tile
    const int ks  = tid >> 5;          // 0..7 k-segment
    const int col = cbase + j;
    const float* Wc = W + col;

    float acc[BATCH_PER_WG];
    #pragma unroll
    for (int b = 0; b < BATCH_PER_WG; ++b) acc[b] = 0.f;

    const int k0 = ks * KSEG;
    #pragma unroll 2
    for (int kk = 0; kk < KSEG; kk += 4) {
        const int k = k0 + kk;
        const float w0 = Wc[(size_t)(k + 0) * N_HID];
        const float w1 = Wc[(size_t)(k + 1) * N_HID];
        const float w2 = Wc[(size_t)(k + 2) * N_HID];
        const float w3 = Wc[(size_t)(k + 3) * N_HID];
        #pragma unroll
        for (int b = 0; b < BATCH_PER_WG; ++b) {
            const float4 h = sh_hy4[b * (N_HID / 4) + (k >> 2)];
            float a = acc[b];
            a = fmaf(h.x, w0, a);
            a = fmaf(h.y, w1, a);
            a = fmaf(h.z, w2, a);
            a = fmaf(h.w, w3, a);
            acc[b] = a;
        }
    }

    #pragma unroll
    for (int b = 0; b < BATCH_PER_WG; ++b)
        sh_part[(ks * BATCH_PER_WG + b) * COLS_PER_WG + j] = acc[b];
    __syncthreads();

    // one output per thread: 8 batches x 32 cols = 256
    {
        const int b  = tid >> 5;
        const int jj = tid & 31;
        float sum = 0.f;
        #pragma unroll
        for (int s2 = 0; s2 < KSPLIT; ++s2)
            sum += sh_part[(s2 * BATCH_PER_WG + b) * COLS_PER_WG + jj];

        const int batch = bbase + b;
        const int c     = cbase + jj;
        const size_t off = (size_t)batch * N_HID + c;

        const float xb  = x[(size_t)batch * TSTEPS + t];
        const float pre = tanhf(fmaf(xb, x2h[c], sum) + bias[c]);
        // old hy from the staged LDS copy (untouched)
        const float hyv = ((const float*)sh_hy4)[b * N_HID + c];
        float hzv = hz[off];
        hzv = fmaf(DT, pre - gam[c] * hyv - eps[c] * hzv, hzv);
        const float hyn = fmaf(DT, hzv, hyv);
        hz[off]    = hzv;
        hyOut[off] = hyn;
        const int s = ((hyn - THETA) > 0.f) ? 1 : 0;
        u[off] = fmaf(u[off], alpha, (float)s * oma);

        const unsigned long long ball = __ballot(s);
        if ((tid & 63) == 0)
            atomicAdd(&sh_cnt, (unsigned)__popcll(ball));
    }
    __syncthreads();
    if (tid == 0) atomicAdd(tot, sh_cnt);
}

__global__ void init_kernel(float* hyA, float* hz, float* u, unsigned int* tot)
{
    const int i = blockIdx.x * blockDim.x + threadIdx.x;
    const int n = NBATCH * N_HID;
    if (i < n) {
        hyA[i] = 0.f;
        hz[i]  = 0.f;
        u[i]   = 0.f;
    }
    if (i == 0) *tot = 0u;
}

__global__ void final_kernel(const unsigned int* __restrict__ tot,
                             float* __restrict__ out_rate)
{
    if (threadIdx.x == 0 && blockIdx.x == 0) {
        const double denom = (double)NBATCH * (double)TSTEPS * (double)N_HID;
        *out_rate = (float)((double)(*tot) / denom);
    }
}

extern "C" void kernel_launch(void* const* d_in, const int* in_sizes, int n_in,
                              void* d_out, int out_size, void* d_ws, size_t ws_size,
                              hipStream_t stream)
{
    const float* x    = (const float*)d_in[0];
    const float* h2h  = (const float*)d_in[1];
    const float* x2h  = (const float*)d_in[2];
    const float* bias = (const float*)d_in[3];
    const float* gam  = (const float*)d_in[4];
    const float* eps  = (const float*)d_in[5];

    float* out = (float*)d_out;           // u: [0, 131072), rate at [131072]
    float* u   = out;

    float* hyA = (float*)d_ws;
    float* hyB = hyA + (size_t)NBATCH * N_HID;
    float* hz  = hyB + (size_t)NBATCH * N_HID;
    unsigned int* tot = (unsigned int*)(hz + (size_t)NBATCH * N_HID);

    init_kernel<<<dim3((NBATCH * N_HID + 255) / 256), dim3(256), 0, stream>>>(
        hyA, hz, u, tot);

    const float alpha = expf(-1.0f / 20.0f);
    const float oma   = 1.0f - alpha;

    const float* src = hyA;
    float* dst = hyB;
    for (int t = 0; t < TSTEPS; ++t) {
        step_kernel<<<dim3(NWG), dim3(256), 0, stream>>>(
            x, h2h, x2h, bias, gam, eps, src, dst, hz, u, tot, t, alpha, oma);
        float* tmp = (float*)src;
        src = dst;
        dst = tmp;
    }

    final_kernel<<<dim3(1), dim3(64), 0, stream>>>(tot, out + (size_t)NBATCH * N_HID);
}

// Round 3
// 5561.198 us; speedup vs baseline: 1.2014x; 1.2014x over previous
//
#include <hip/hip_runtime.h>
#include <math.h>

#define N_HID   1024
#define NBATCH  128
#define TSTEPS  500
#define DT      0.05f
#define THETA   0.1f

// Tiling: WG = 256 threads computes a 16-batch x 32-col output tile, k-split 8.
// Thread tile: 4 batches x 4 cols (16 acc), k-segment of 128.
// Grid = 8 batch-tiles x 32 col-tiles = 256 WGs (1 per CU).
// Summation order: ascending k within each 128-seg (one fmaf per k per
// output), then segments 0..7 summed ascending — matches the v1 kernel that
// validated bit-exact (absmax 0.0).
#define B_WG   16
#define C_WG   32
#define KSPL   8
#define KSEG   (N_HID / KSPL)      // 128
#define NWG    ((NBATCH / B_WG) * (N_HID / C_WG))   // 8*32 = 256

// hy is stored TRANSPOSED in workspace: hyT[n_hid][n_batch] so the GEMM
// reads hyT[k][b0:b0+4] as one float4 from LDS.

__global__ __launch_bounds__(256, 1) void step_kernel(
    const float* __restrict__ x,
    const float* __restrict__ W,       // (1024,1024) row-major [k][c]
    const float* __restrict__ x2h,
    const float* __restrict__ bias,
    const float* __restrict__ gam,
    const float* __restrict__ eps,
    const float* __restrict__ hyTin,   // (1024,128) [hid][batch]
    float* __restrict__ hyTout,
    float* __restrict__ hz,            // (128,1024) [batch][hid]
    float* __restrict__ u,
    unsigned int* __restrict__ tot,
    int t, float alpha, float oma)
{
    __shared__ float sh_hyT[N_HID * B_WG];                 // 64 KB: [k][16 b]
    __shared__ float sh_part[KSPL * B_WG * C_WG];          // 16 KB: [ks][b][c]
    __shared__ float sh_out[C_WG * (B_WG + 1)];            // padded transpose buf
    __shared__ unsigned int sh_cnt;

    const int tid = threadIdx.x;
    if (tid == 0) sh_cnt = 0u;

    // XCD swizzle: XCD (bid&7) owns 4 consecutive col-tiles (128 cols, 512 KB
    // of W) -> W slice stays resident in that XCD's L2 across the 8 b-tiles.
    const int bid   = blockIdx.x;
    const int xcd   = bid & 7;
    const int idx   = bid >> 3;            // 0..31
    const int ctile = xcd * 4 + (idx & 3); // 0..31
    const int btile = idx >> 2;            // 0..7
    const int c0g   = ctile * C_WG;        // global col base
    const int b0    = btile * B_WG;        // global batch base

    // ---- stage hyT[:, b0:b0+16] -> LDS (64 KB), coalesced float4 ----
    {
        const float4* g4 = (const float4*)hyTin;   // row = 32 float4
        float4* s4 = (float4*)sh_hyT;              // [k][4 chunks]
        #pragma unroll
        for (int it = 0; it < 16; ++it) {
            const int i = it * 256 + tid;          // 0..4095
            const int k = i >> 2, ch = i & 3;
            s4[i] = g4[k * 32 + btile * 4 + ch];
        }
    }
    __syncthreads();

    // ---- register-blocked GEMM: 4b x 4c per thread, kseg = 128 ----
    const int cg = tid & 7;            // 8 col-groups of 4
    const int bg = (tid >> 3) & 3;     // 4 batch-groups of 4
    const int ks = tid >> 5;           // 8 k-segments
    const int bl0 = bg * 4;
    const int k0  = ks * KSEG;
    const float* Wp = W + (size_t)k0 * N_HID + c0g + cg * 4;

    float acc[4][4];
    #pragma unroll
    for (int i = 0; i < 4; ++i)
        #pragma unroll
        for (int j = 0; j < 4; ++j) acc[i][j] = 0.f;

    #pragma unroll 8
    for (int kk = 0; kk < KSEG; ++kk) {
        const float4 hv = *(const float4*)(&sh_hyT[(k0 + kk) * B_WG + bl0]);
        const float4 wv = *(const float4*)(Wp + (size_t)kk * N_HID);
        acc[0][0] = fmaf(hv.x, wv.x, acc[0][0]);
        acc[0][1] = fmaf(hv.x, wv.y, acc[0][1]);
        acc[0][2] = fmaf(hv.x, wv.z, acc[0][2]);
        acc[0][3] = fmaf(hv.x, wv.w, acc[0][3]);
        acc[1][0] = fmaf(hv.y, wv.x, acc[1][0]);
        acc[1][1] = fmaf(hv.y, wv.y, acc[1][1]);
        acc[1][2] = fmaf(hv.y, wv.z, acc[1][2]);
        acc[1][3] = fmaf(hv.y, wv.w, acc[1][3]);
        acc[2][0] = fmaf(hv.z, wv.x, acc[2][0]);
        acc[2][1] = fmaf(hv.z, wv.y, acc[2][1]);
        acc[2][2] = fmaf(hv.z, wv.z, acc[2][2]);
        acc[2][3] = fmaf(hv.z, wv.w, acc[2][3]);
        acc[3][0] = fmaf(hv.w, wv.x, acc[3][0]);
        acc[3][1] = fmaf(hv.w, wv.y, acc[3][1]);
        acc[3][2] = fmaf(hv.w, wv.z, acc[3][2]);
        acc[3][3] = fmaf(hv.w, wv.w, acc[3][3]);
    }

    #pragma unroll
    for (int bi = 0; bi < 4; ++bi) {
        float4 v = make_float4(acc[bi][0], acc[bi][1], acc[bi][2], acc[bi][3]);
        *(float4*)(&sh_part[((ks * B_WG) + bl0 + bi) * C_WG + cg * 4]) = v;
    }
    __syncthreads();

    // ---- reduce over k-segments (ascending, order-preserving) + epilogue ----
    unsigned int myspikes = 0;
    #pragma unroll
    for (int half = 0; half < 2; ++half) {
        const int e  = half * 256 + tid;   // 0..511
        const int bl = e >> 5;             // 0..15 (half0: 0..7, half1: 8..15)
        const int c  = e & 31;
        float sum = sh_part[(0 * B_WG + bl) * C_WG + c];
        #pragma unroll
        for (int s2 = 1; s2 < KSPL; ++s2)
            sum += sh_part[(s2 * B_WG + bl) * C_WG + c];

        const int batch = b0 + bl;
        const int cgl   = c0g + c;
        const size_t off = (size_t)batch * N_HID + cgl;

        const float xb  = x[(size_t)batch * TSTEPS + t];
        const float pre = tanhf(fmaf(xb, x2h[cgl], sum) + bias[cgl]);
        const float hyv = sh_hyT[cgl * B_WG + bl];   // old hy (staged)
        float hzv = hz[off];
        hzv = fmaf(DT, pre - gam[cgl] * hyv - eps[cgl] * hzv, hzv);
        const float hyn = fmaf(DT, hzv, hyv);
        hz[off] = hzv;
        const int s = ((hyn - THETA) > 0.f) ? 1 : 0;
        u[off] = fmaf(u[off], alpha, (float)s * oma);
        myspikes += (unsigned)s;

        sh_out[c * (B_WG + 1) + bl] = hyn; // padded: no bank conflict
    }
    __syncthreads();   // all 512 sh_out entries valid

    // single coalesced transposed write: hyTout[c0g+c2][b0:b0+16]
    {
        const int c2 = tid >> 3;           // 0..31
        const int b2 = (tid & 7) * 2;      // 0,2,..,14
        float* dst = hyTout + (size_t)(c0g + c2) * NBATCH + b0 + b2;
        dst[0] = sh_out[c2 * (B_WG + 1) + b2];
        dst[1] = sh_out[c2 * (B_WG + 1) + b2 + 1];
    }

    // spike count: wave-reduce (bit1 lanes carry TWO spikes) then one atomic
    {
        unsigned long long ball0 = __ballot(myspikes & 1u);
        unsigned long long ball1 = __ballot((myspikes >> 1) & 1u);
        if ((tid & 63) == 0) {
            unsigned int cnt = (unsigned)__popcll(ball0)
                             + 2u * (unsigned)__popcll(ball1);
            atomicAdd(&sh_cnt, cnt);
        }
    }
    __syncthreads();
    if (tid == 0) atomicAdd(tot, sh_cnt);
}

__global__ void init_kernel(float* hyTA, float* hz, float* u, unsigned int* tot)
{
    const int i = blockIdx.x * blockDim.x + threadIdx.x;
    const int n = NBATCH * N_HID;
    if (i < n) {
        hyTA[i] = 0.f;
        hz[i]   = 0.f;
        u[i]    = 0.f;
    }
    if (i == 0) *tot = 0u;
}

__global__ void final_kernel(const unsigned int* __restrict__ tot,
                             float* __restrict__ out_rate)
{
    if (threadIdx.x == 0 && blockIdx.x == 0) {
        const double denom = (double)NBATCH * (double)TSTEPS * (double)N_HID;
        *out_rate = (float)((double)(*tot) / denom);
    }
}

extern "C" void kernel_launch(void* const* d_in, const int* in_sizes, int n_in,
                              void* d_out, int out_size, void* d_ws, size_t ws_size,
                              hipStream_t stream)
{
    const float* x    = (const float*)d_in[0];
    const float* h2h  = (const float*)d_in[1];
    const float* x2h  = (const float*)d_in[2];
    const float* bias = (const float*)d_in[3];
    const float* gam  = (const float*)d_in[4];
    const float* eps  = (const float*)d_in[5];

    float* out = (float*)d_out;            // u: [0,131072), rate at [131072]
    float* u   = out;

    float* hyTA = (float*)d_ws;
    float* hyTB = hyTA + (size_t)NBATCH * N_HID;
    float* hz   = hyTB + (size_t)NBATCH * N_HID;
    unsigned int* tot = (unsigned int*)(hz + (size_t)NBATCH * N_HID);

    init_kernel<<<dim3((NBATCH * N_HID + 255) / 256), dim3(256), 0, stream>>>(
        hyTA, hz, u, tot);

    const float alpha = expf(-1.0f / 20.0f);
    const float oma   = 1.0f - alpha;

    const float* src = hyTA;
    float* dst = hyTB;
    for (int t = 0; t < TSTEPS; ++t) {
        step_kernel<<<dim3(NWG), dim3(256), 0, stream>>>(
            x, h2h, x2h, bias, gam, eps, src, dst, hz, u, tot, t, alpha, oma);
        float* tmp = (float*)src;
        src = dst;
        dst = tmp;
    }

    final_kernel<<<dim3(1), dim3(64), 0, stream>>>(tot, out + (size_t)NBATCH * N_HID);
}